// Round 1
// baseline (1185.471 us; speedup 1.0000x reference)
//
#include <hip/hip_runtime.h>

// Problem constants (from setup_inputs)
#define NB      512          // number of blocks
#define NSAMP   2101312L     // y samples per pol
#define SOUT    2048         // downsampled symbols per block per pol
#define LOFF    12           // (L-1)/2 for h_est L=25
#define NEDGE   12
#define NJ      4072         // N - L + 1
#define CHUNK   512
#define NCHUNK  4
#define STAGE   544          // CHUNK + 32 (max polyphase window extension)

#define OUTY_OFF   0
#define OUTQ_OFF   4194304L
#define OUTVAR_OFF (4194304L + 67108864L)

__global__ __launch_bounds__(512, 4)
void vae_elbo_kernel(const float* __restrict__ y,
                     const float* __restrict__ taps,   // (2,2,65,2)
                     const float* __restrict__ h_est,  // (2,2,2,25)
                     const float* __restrict__ amp,    // (16)
                     const float* __restrict__ p_sym,  // (16)
                     const float* __restrict__ nsig,   // (1)
                     float* __restrict__ out)
{
    const int k   = blockIdx.x;
    const int tid = threadIdx.x;
    const long Bk = (long)k * 4096;   // window base sample index

    float* const out_y    = out + OUTY_OFF;
    float* const out_q    = out + OUTQ_OFF;
    float* const out_var  = out + OUTVAR_OFF;
    float* const out_loss = out + OUTVAR_OFF + 2;

    // Polyphase staging: even/odd input samples, SoA re/im, per input pol.
    __shared__ float xer[2][STAGE], xei[2][STAGE];
    __shared__ float xodr[2][STAGE], xodi[2][STAGE];
    __shared__ float E0L[2][SOUT], E1L[2][SOUT];
    __shared__ float Vlo[2][NEDGE], Vhi[2][NEDGE];
    __shared__ float red[8][12];

    const float sg = nsig[0];
    const float inv2s2 = 1.0f / (2.0f * sg * sg);

    // Uniform per-symbol constants (amps stay SGPR; ivp needs VALU rcp -> regs)
    float amps[16], ivp[16];
    #pragma unroll
    for (int c = 0; c < 16; ++c) {
        amps[c] = amp[c];
        ivp[c]  = 1.0f / p_sym[c];
    }

    float kl_acc = 0.0f;
    float vt0 = 0.0f, vt1 = 0.0f;

    // ---------------- Phase 1: FIR conv + demap + moments ----------------
    for (int cn = 0; cn < NCHUNK; ++cn) {
        const int s0 = cn * CHUNK;
        __syncthreads();
        {
            const float4* y4 = (const float4*)y;  // one float4 = (re[n],im[n],re[n+1],im[n+1])
            #pragma unroll
            for (int it = 0; it < 3; ++it) {
                int idx = tid + it * 512;
                if (idx < 2 * STAGE) {
                    int i = (idx >= STAGE) ? 1 : 0;
                    int u = idx - i * STAGE;
                    float4 v = y4[(((long)i * NSAMP + Bk) >> 1) + s0 + u];
                    xer[i][u]  = v.x; xei[i][u]  = v.y;
                    xodr[i][u] = v.z; xodi[i][u] = v.w;
                }
            }
        }
        __syncthreads();

        const int s = s0 + tid;

        // conv: both output pols fused over one x read
        float ar0 = 0.f, ai0 = 0.f, ar1 = 0.f, ai1 = 0.f;
        #pragma unroll
        for (int i = 0; i < 2; ++i) {
            const float* tA = taps + i * 130;         // o=0: ((0*2+i)*65+l)*2
            const float* tB = taps + 260 + i * 130;   // o=1
            #pragma unroll
            for (int m = 0; m <= 32; ++m) {           // even taps l=2m
                float xr = xer[i][tid + m], xi = xei[i][tid + m];
                float wr = tA[4*m], wi = tA[4*m + 1];
                ar0 = fmaf(xr, wr, ar0); ar0 = fmaf(-xi, wi, ar0);
                ai0 = fmaf(xr, wi, ai0); ai0 = fmaf( xi, wr, ai0);
                wr = tB[4*m]; wi = tB[4*m + 1];
                ar1 = fmaf(xr, wr, ar1); ar1 = fmaf(-xi, wi, ar1);
                ai1 = fmaf(xr, wi, ai1); ai1 = fmaf( xi, wr, ai1);
            }
            #pragma unroll
            for (int m = 0; m < 32; ++m) {            // odd taps l=2m+1
                float xr = xodr[i][tid + m], xi = xodi[i][tid + m];
                float wr = tA[4*m + 2], wi = tA[4*m + 3];
                ar0 = fmaf(xr, wr, ar0); ar0 = fmaf(-xi, wi, ar0);
                ai0 = fmaf(xr, wi, ai0); ai0 = fmaf( xi, wr, ai0);
                wr = tB[4*m + 2]; wi = tB[4*m + 3];
                ar1 = fmaf(xr, wr, ar1); ar1 = fmaf(-xi, wi, ar1);
                ai1 = fmaf(xr, wi, ai1); ai1 = fmaf( xi, wr, ai1);
            }
        }

        #pragma unroll
        for (int o = 0; o < 2; ++o) {
            const float yhr = o ? ar1 : ar0;
            const float yhi = o ? ai1 : ai0;

            float qv[32];
            float E0 = 0.f, E1 = 0.f, Vs = 0.f;
            {   // real-part softmax (uniform logp dropped: softmax shift-invariant)
                float z[16], zm = -3.0e38f;
                #pragma unroll
                for (int c = 0; c < 16; ++c) {
                    float d = yhr - amps[c];
                    z[c] = -d * d * inv2s2;
                    zm = fmaxf(zm, z[c]);
                }
                float se = 0.f;
                #pragma unroll
                for (int c = 0; c < 16; ++c) { z[c] = __expf(z[c] - zm); se += z[c]; }
                float inv = 1.0f / se;
                #pragma unroll
                for (int c = 0; c < 16; ++c) {
                    float q = z[c] * inv;
                    qv[c] = q;
                    E0 = fmaf(q, amps[c], E0);
                    Vs = fmaf(q, amps[c] * amps[c], Vs);
                }
            }
            {   // imag-part softmax
                float z[16], zm = -3.0e38f;
                #pragma unroll
                for (int c = 0; c < 16; ++c) {
                    float d = yhi - amps[c];
                    z[c] = -d * d * inv2s2;
                    zm = fmaxf(zm, z[c]);
                }
                float se = 0.f;
                #pragma unroll
                for (int c = 0; c < 16; ++c) { z[c] = __expf(z[c] - zm); se += z[c]; }
                float inv = 1.0f / se;
                #pragma unroll
                for (int c = 0; c < 16; ++c) {
                    float q = z[c] * inv;
                    qv[16 + c] = q;
                    E1 = fmaf(q, amps[c], E1);
                    Vs = fmaf(q, amps[c] * amps[c], Vs);
                }
            }
            Vs = Vs - E0 * E0 - E1 * E1;

            E0L[o][s] = E0;
            E1L[o][s] = E1;
            if (o == 0) vt0 += Vs; else vt1 += Vs;
            if (s < NEDGE)          Vlo[o][s] = Vs;
            if (s >= SOUT - NEDGE)  Vhi[o][s - (SOUT - NEDGE)] = Vs;

            if (s >= LOFF && s < SOUT - LOFF) {
                float klp = 0.f;
                #pragma unroll
                for (int c = 0; c < 32; ++c)
                    klp += qv[c] * __logf(fmaf(qv[c], ivp[c & 15], 1e-14f));
                kl_acc += klp;
            }

            const long gy = ((long)(o * NB + k)) * SOUT + s;
            ((float2*)out_y)[gy] = make_float2(yhr, yhi);
            float4* oq = (float4*)(out_q + gy * 32);
            #pragma unroll
            for (int w = 0; w < 8; ++w)
                oq[w] = make_float4(qv[4*w], qv[4*w+1], qv[4*w+2], qv[4*w+3]);
        }
    }
    __syncthreads();

    // ---------------- Phase 2: D = conv(upsampled E, h) [24:4096), C terms ----
    float sy2[2] = {0.f, 0.f}, syd[2] = {0.f, 0.f}, sd2[2] = {0.f, 0.f};
    const float2* y2 = (const float2*)y;
    #pragma unroll
    for (int par = 0; par < 2; ++par) {
        const int mcnt = 13 - par;   // taps with matching parity
        for (int r = 0; r < 4; ++r) {
            const int t2 = tid + r * 512;
            if (t2 < SOUT - LOFF) {          // t2 in [0, 2036)
                const int j  = 2 * t2 + par; // output index in [0, 4072)
                const int sb = t2 + LOFF;    // (n - par)/2, n = j + 24
                float dr0 = 0.f, di0 = 0.f, dr1 = 0.f, di1 = 0.f;
                #pragma unroll
                for (int i = 0; i < 2; ++i) {
                    #pragma unroll
                    for (int m = 0; m < mcnt; ++m) {
                        const int l = 2 * m + par;
                        const float e0 = E0L[i][sb - m];
                        const float e1 = E1L[i][sb - m];
                        float hr = h_est[((0 * 2 + i) * 2 + 0) * 25 + l];
                        float hi = h_est[((0 * 2 + i) * 2 + 1) * 25 + l];
                        dr0 += e0 * hr - e1 * hi;
                        di0 += e0 * hi + e1 * hr;
                        hr = h_est[((1 * 2 + i) * 2 + 0) * 25 + l];
                        hi = h_est[((1 * 2 + i) * 2 + 1) * 25 + l];
                        dr1 += e0 * hr - e1 * hi;
                        di1 += e0 * hi + e1 * hr;
                    }
                }
                float2 yv = y2[Bk + 44 + j];               // p=0: y[0, 4096k+32+12+j]
                sy2[0] += yv.x * yv.x + yv.y * yv.y;
                syd[0] += yv.x * dr0 + yv.y * di0;
                sd2[0] += dr0 * dr0 + di0 * di0;
                yv = y2[NSAMP + Bk + 44 + j];              // p=1
                sy2[1] += yv.x * yv.x + yv.y * yv.y;
                syd[1] += yv.x * dr1 + yv.y * di1;
                sd2[1] += dr1 * dr1 + di1 * di1;
            }
        }
    }

    // ---------------- Reduction + finalize ----------------
    float vals[9] = {kl_acc, vt0, vt1, sy2[0], sy2[1], syd[0], syd[1], sd2[0], sd2[1]};
    #pragma unroll
    for (int d = 32; d >= 1; d >>= 1) {
        #pragma unroll
        for (int v = 0; v < 9; ++v)
            vals[v] += __shfl_down(vals[v], (unsigned)d, 64);
    }
    const int wv = tid >> 6;
    if ((tid & 63) == 0) {
        #pragma unroll
        for (int v = 0; v < 9; ++v) red[wv][v] = vals[v];
    }
    __syncthreads();

    if (tid == 0) {
        float tot[9];
        #pragma unroll
        for (int v = 0; v < 9; ++v) {
            float t = 0.f;
            #pragma unroll
            for (int w = 0; w < 8; ++w) t += red[w][v];
            tot[v] = t;
        }
        // E term: Wsum[i][l] = Vtot - (excluded prefix) - (excluded suffix)
        float Et0 = 0.f, Et1 = 0.f;
        #pragma unroll
        for (int i = 0; i < 2; ++i) {
            const float Vt = (i == 0) ? tot[1] : tot[2];
            float plo[13], phi[13];
            plo[0] = 0.f; phi[0] = 0.f;
            #pragma unroll
            for (int t = 0; t < 12; ++t) {
                plo[t + 1] = plo[t] + Vlo[i][t];
                phi[t + 1] = phi[t] + Vhi[i][11 - t];
            }
            #pragma unroll
            for (int l = 0; l < 25; ++l) {
                int lo, hi;
                if ((l & 1) == 0) { lo = 12 - l / 2;     hi = l / 2; }
                else             { lo = (25 - l) / 2;    hi = (l - 1) / 2; }
                const float ws = Vt - plo[lo] - phi[hi];
                const float h00 = h_est[((0 * 2 + i) * 2 + 0) * 25 + l];
                const float h01 = h_est[((0 * 2 + i) * 2 + 1) * 25 + l];
                const float h10 = h_est[((1 * 2 + i) * 2 + 0) * 25 + l];
                const float h11 = h_est[((1 * 2 + i) * 2 + 1) * 25 + l];
                Et0 += (h00 * h00 + h01 * h01) * ws;
                Et1 += (h10 * h10 + h11 * h11) * ws;
            }
        }
        const float C0 = tot[3] - 2.0f * tot[5] + tot[7] + Et0;
        const float C1 = tot[4] - 2.0f * tot[6] + tot[8] + Et1;
        const float loss = tot[0] + 4072.0f * (logf(C0 + 1e-8f) + logf(C1 + 1e-8f));
        out_loss[k] = loss;
        if (k == NB - 1) {
            out_var[0] = C0 / 4072.0f;
            out_var[1] = C1 / 4072.0f;
        }
    }
}

extern "C" void kernel_launch(void* const* d_in, const int* in_sizes, int n_in,
                              void* d_out, int out_size, void* d_ws, size_t ws_size,
                              hipStream_t stream) {
    const float* y     = (const float*)d_in[0];
    const float* taps  = (const float*)d_in[1];
    const float* h_est = (const float*)d_in[2];
    const float* amp   = (const float*)d_in[3];
    const float* p_sym = (const float*)d_in[4];
    const float* nsig  = (const float*)d_in[5];
    (void)in_sizes; (void)n_in; (void)out_size; (void)d_ws; (void)ws_size;

    vae_elbo_kernel<<<NB, 512, 0, stream>>>(y, taps, h_est, amp, p_sym, nsig,
                                            (float*)d_out);
}

// Round 2
// 1111.937 us; speedup vs baseline: 1.0661x; 1.0661x over previous
//
#include <hip/hip_runtime.h>

// Problem constants (from setup_inputs)
#define NB      512          // number of blocks
#define NSAMP   2101312L     // y samples per pol
#define SOUT    2048         // downsampled symbols per block per pol
#define LOFF    12           // (L-1)/2 for h_est L=25
#define NEDGE   12
#define NJ      4072         // N - L + 1
#define CHUNK   512
#define NCHUNK  4
#define STAGE   544          // CHUNK + 32 (max polyphase window extension)
#define QROWS   256          // symbols per q-store sub-tile
#define QPAD    36           // row stride in floats (16B-aligned, bank-spread)

#define OUTY_OFF   0
#define OUTQ_OFF   4194304L
#define OUTVAR_OFF (4194304L + 67108864L)

__global__ __launch_bounds__(512, 4)
void vae_elbo_kernel(const float* __restrict__ y,
                     const float* __restrict__ taps,   // (2,2,65,2)
                     const float* __restrict__ h_est,  // (2,2,2,25)
                     const float* __restrict__ amp,    // (16)
                     const float* __restrict__ p_sym,  // (16)
                     const float* __restrict__ nsig,   // (1)
                     float* __restrict__ out)
{
    const int k   = blockIdx.x;
    const int tid = threadIdx.x;
    const long Bk = (long)k * 4096;   // window base sample index

    float* const out_y    = out + OUTY_OFF;
    float* const out_q    = out + OUTQ_OFF;
    float* const out_var  = out + OUTVAR_OFF;
    float* const out_loss = out + OUTVAR_OFF + 2;

    // FIR polyphase staging unioned with the q-transpose buffer (x is dead
    // by the time q is staged; next chunk's restage is barrier-protected).
    __shared__ union {
        struct { float er[2][STAGE], ei[2][STAGE], odr[2][STAGE], odi[2][STAGE]; } x;
        float qbuf[QROWS * QPAD];   // 256 rows x 36 floats (row = one symbol's 32 q + pad)
    } sh;
    __shared__ float E0L[2][SOUT], E1L[2][SOUT];
    __shared__ float Vlo[2][NEDGE], Vhi[2][NEDGE];
    __shared__ float red[8][12];

    const float sg = nsig[0];
    const float inv2s2 = 1.0f / (2.0f * sg * sg);

    float amps[16], ivp[16];
    #pragma unroll
    for (int c = 0; c < 16; ++c) {
        amps[c] = amp[c];
        ivp[c]  = 1.0f / p_sym[c];
    }

    float kl_acc = 0.0f;
    float vt0 = 0.0f, vt1 = 0.0f;

    // ---------------- Phase 1: FIR conv + demap + moments + q store ----------------
    for (int cn = 0; cn < NCHUNK; ++cn) {
        const int s0 = cn * CHUNK;
        __syncthreads();   // prior chunk's qbuf reads complete
        {
            const float4* y4 = (const float4*)y;  // (re[n],im[n],re[n+1],im[n+1])
            #pragma unroll
            for (int it = 0; it < 3; ++it) {
                int idx = tid + it * 512;
                if (idx < 2 * STAGE) {
                    int i = (idx >= STAGE) ? 1 : 0;
                    int u = idx - i * STAGE;
                    float4 v = y4[(((long)i * NSAMP + Bk) >> 1) + s0 + u];
                    sh.x.er[i][u]  = v.x; sh.x.ei[i][u]  = v.y;
                    sh.x.odr[i][u] = v.z; sh.x.odi[i][u] = v.w;
                }
            }
        }
        __syncthreads();

        const int s = s0 + tid;

        // conv: both output pols fused over one x read
        float ar0 = 0.f, ai0 = 0.f, ar1 = 0.f, ai1 = 0.f;
        #pragma unroll
        for (int i = 0; i < 2; ++i) {
            const float* tA = taps + i * 130;         // o=0
            const float* tB = taps + 260 + i * 130;   // o=1
            #pragma unroll
            for (int m = 0; m <= 32; ++m) {           // even taps l=2m
                float xr = sh.x.er[i][tid + m], xi = sh.x.ei[i][tid + m];
                float wr = tA[4*m], wi = tA[4*m + 1];
                ar0 = fmaf(xr, wr, ar0); ar0 = fmaf(-xi, wi, ar0);
                ai0 = fmaf(xr, wi, ai0); ai0 = fmaf( xi, wr, ai0);
                wr = tB[4*m]; wi = tB[4*m + 1];
                ar1 = fmaf(xr, wr, ar1); ar1 = fmaf(-xi, wi, ar1);
                ai1 = fmaf(xr, wi, ai1); ai1 = fmaf( xi, wr, ai1);
            }
            #pragma unroll
            for (int m = 0; m < 32; ++m) {            // odd taps l=2m+1
                float xr = sh.x.odr[i][tid + m], xi = sh.x.odi[i][tid + m];
                float wr = tA[4*m + 2], wi = tA[4*m + 3];
                ar0 = fmaf(xr, wr, ar0); ar0 = fmaf(-xi, wi, ar0);
                ai0 = fmaf(xr, wi, ai0); ai0 = fmaf( xi, wr, ai0);
                wr = tB[4*m + 2]; wi = tB[4*m + 3];
                ar1 = fmaf(xr, wr, ar1); ar1 = fmaf(-xi, wi, ar1);
                ai1 = fmaf(xr, wi, ai1); ai1 = fmaf( xi, wr, ai1);
            }
        }

        #pragma unroll
        for (int o = 0; o < 2; ++o) {
            const float yhr = o ? ar1 : ar0;
            const float yhi = o ? ai1 : ai0;

            float qv[32];
            float E0 = 0.f, E1 = 0.f, Vs = 0.f;
            {   // real-part softmax (uniform logp dropped: shift-invariant)
                float z[16], zm = -3.0e38f;
                #pragma unroll
                for (int c = 0; c < 16; ++c) {
                    float d = yhr - amps[c];
                    z[c] = -d * d * inv2s2;
                    zm = fmaxf(zm, z[c]);
                }
                float se = 0.f;
                #pragma unroll
                for (int c = 0; c < 16; ++c) { z[c] = __expf(z[c] - zm); se += z[c]; }
                float inv = 1.0f / se;
                #pragma unroll
                for (int c = 0; c < 16; ++c) {
                    float q = z[c] * inv;
                    qv[c] = q;
                    E0 = fmaf(q, amps[c], E0);
                    Vs = fmaf(q, amps[c] * amps[c], Vs);
                }
            }
            {   // imag-part softmax
                float z[16], zm = -3.0e38f;
                #pragma unroll
                for (int c = 0; c < 16; ++c) {
                    float d = yhi - amps[c];
                    z[c] = -d * d * inv2s2;
                    zm = fmaxf(zm, z[c]);
                }
                float se = 0.f;
                #pragma unroll
                for (int c = 0; c < 16; ++c) { z[c] = __expf(z[c] - zm); se += z[c]; }
                float inv = 1.0f / se;
                #pragma unroll
                for (int c = 0; c < 16; ++c) {
                    float q = z[c] * inv;
                    qv[16 + c] = q;
                    E1 = fmaf(q, amps[c], E1);
                    Vs = fmaf(q, amps[c] * amps[c], Vs);
                }
            }
            Vs = Vs - E0 * E0 - E1 * E1;

            E0L[o][s] = E0;
            E1L[o][s] = E1;
            if (o == 0) vt0 += Vs; else vt1 += Vs;
            if (s < NEDGE)          Vlo[o][s] = Vs;
            if (s >= SOUT - NEDGE)  Vhi[o][s - (SOUT - NEDGE)] = Vs;

            if (s >= LOFF && s < SOUT - LOFF) {
                float klp = 0.f;
                #pragma unroll
                for (int c = 0; c < 32; ++c)
                    klp += qv[c] * __logf(fmaf(qv[c], ivp[c & 15], 1e-14f));
                kl_acc += klp;
            }

            const long gy = ((long)(o * NB + k)) * SOUT + s;
            ((float2*)out_y)[gy] = make_float2(yhr, yhi);

            // q store: transpose through LDS, then lane-dense dwordx4 stores.
            #pragma unroll
            for (int st = 0; st < 2; ++st) {
                __syncthreads();   // (st=0,o=0): conv x reads done; else prior reads done
                if ((tid >> 8) == st) {
                    const int r = tid & 255;
                    #pragma unroll
                    for (int c = 0; c < 32; c += 4)
                        *(float4*)&sh.qbuf[r * QPAD + c] =
                            make_float4(qv[c], qv[c+1], qv[c+2], qv[c+3]);
                }
                __syncthreads();
                const long gb32 = (((long)(o * NB + k)) * SOUT + s0 + st * QROWS) * 32;
                #pragma unroll
                for (int u = 0; u < 4; ++u) {
                    const int f   = u * 2048 + tid * 4;      // lane-dense
                    const int sym = u * 64 + (tid >> 3);
                    const int c   = (tid & 7) * 4;
                    float4 v = *(const float4*)&sh.qbuf[sym * QPAD + c];
                    *(float4*)&out_q[gb32 + f] = v;
                }
            }
        }
    }
    __syncthreads();

    // ---------------- Phase 2: D = conv(upsampled E, h) [24:4096), C terms ----
    float sy2[2] = {0.f, 0.f}, syd[2] = {0.f, 0.f}, sd2[2] = {0.f, 0.f};
    const float2* y2 = (const float2*)y;
    #pragma unroll
    for (int par = 0; par < 2; ++par) {
        const int mcnt = 13 - par;   // taps with matching parity
        for (int r = 0; r < 4; ++r) {
            const int t2 = tid + r * 512;
            if (t2 < SOUT - LOFF) {          // t2 in [0, 2036)
                const int j  = 2 * t2 + par; // output index in [0, 4072)
                const int sb = t2 + LOFF;
                float dr0 = 0.f, di0 = 0.f, dr1 = 0.f, di1 = 0.f;
                #pragma unroll
                for (int i = 0; i < 2; ++i) {
                    #pragma unroll
                    for (int m = 0; m < mcnt; ++m) {
                        const int l = 2 * m + par;
                        const float e0 = E0L[i][sb - m];
                        const float e1 = E1L[i][sb - m];
                        float hr = h_est[((0 * 2 + i) * 2 + 0) * 25 + l];
                        float hi = h_est[((0 * 2 + i) * 2 + 1) * 25 + l];
                        dr0 += e0 * hr - e1 * hi;
                        di0 += e0 * hi + e1 * hr;
                        hr = h_est[((1 * 2 + i) * 2 + 0) * 25 + l];
                        hi = h_est[((1 * 2 + i) * 2 + 1) * 25 + l];
                        dr1 += e0 * hr - e1 * hi;
                        di1 += e0 * hi + e1 * hr;
                    }
                }
                float2 yv = y2[Bk + 44 + j];               // p=0
                sy2[0] += yv.x * yv.x + yv.y * yv.y;
                syd[0] += yv.x * dr0 + yv.y * di0;
                sd2[0] += dr0 * dr0 + di0 * di0;
                yv = y2[NSAMP + Bk + 44 + j];              // p=1
                sy2[1] += yv.x * yv.x + yv.y * yv.y;
                syd[1] += yv.x * dr1 + yv.y * di1;
                sd2[1] += dr1 * dr1 + di1 * di1;
            }
        }
    }

    // ---------------- Reduction + finalize ----------------
    float vals[9] = {kl_acc, vt0, vt1, sy2[0], sy2[1], syd[0], syd[1], sd2[0], sd2[1]};
    #pragma unroll
    for (int d = 32; d >= 1; d >>= 1) {
        #pragma unroll
        for (int v = 0; v < 9; ++v)
            vals[v] += __shfl_down(vals[v], (unsigned)d, 64);
    }
    const int wv = tid >> 6;
    if ((tid & 63) == 0) {
        #pragma unroll
        for (int v = 0; v < 9; ++v) red[wv][v] = vals[v];
    }
    __syncthreads();

    if (tid == 0) {
        float tot[9];
        #pragma unroll
        for (int v = 0; v < 9; ++v) {
            float t = 0.f;
            #pragma unroll
            for (int w = 0; w < 8; ++w) t += red[w][v];
            tot[v] = t;
        }
        float Et0 = 0.f, Et1 = 0.f;
        #pragma unroll
        for (int i = 0; i < 2; ++i) {
            const float Vt = (i == 0) ? tot[1] : tot[2];
            float plo[13], phi[13];
            plo[0] = 0.f; phi[0] = 0.f;
            #pragma unroll
            for (int t = 0; t < 12; ++t) {
                plo[t + 1] = plo[t] + Vlo[i][t];
                phi[t + 1] = phi[t] + Vhi[i][11 - t];
            }
            #pragma unroll
            for (int l = 0; l < 25; ++l) {
                int lo, hi;
                if ((l & 1) == 0) { lo = 12 - l / 2;     hi = l / 2; }
                else             { lo = (25 - l) / 2;    hi = (l - 1) / 2; }
                const float ws = Vt - plo[lo] - phi[hi];
                const float h00 = h_est[((0 * 2 + i) * 2 + 0) * 25 + l];
                const float h01 = h_est[((0 * 2 + i) * 2 + 1) * 25 + l];
                const float h10 = h_est[((1 * 2 + i) * 2 + 0) * 25 + l];
                const float h11 = h_est[((1 * 2 + i) * 2 + 1) * 25 + l];
                Et0 += (h00 * h00 + h01 * h01) * ws;
                Et1 += (h10 * h10 + h11 * h11) * ws;
            }
        }
        const float C0 = tot[3] - 2.0f * tot[5] + tot[7] + Et0;
        const float C1 = tot[4] - 2.0f * tot[6] + tot[8] + Et1;
        const float loss = tot[0] + 4072.0f * (logf(C0 + 1e-8f) + logf(C1 + 1e-8f));
        out_loss[k] = loss;
        if (k == NB - 1) {
            out_var[0] = C0 / 4072.0f;
            out_var[1] = C1 / 4072.0f;
        }
    }
}

extern "C" void kernel_launch(void* const* d_in, const int* in_sizes, int n_in,
                              void* d_out, int out_size, void* d_ws, size_t ws_size,
                              hipStream_t stream) {
    const float* y     = (const float*)d_in[0];
    const float* taps  = (const float*)d_in[1];
    const float* h_est = (const float*)d_in[2];
    const float* amp   = (const float*)d_in[3];
    const float* p_sym = (const float*)d_in[4];
    const float* nsig  = (const float*)d_in[5];
    (void)in_sizes; (void)n_in; (void)out_size; (void)d_ws; (void)ws_size;

    vae_elbo_kernel<<<NB, 512, 0, stream>>>(y, taps, h_est, amp, p_sym, nsig,
                                            (float*)d_out);
}